// Round 17
// baseline (91.846 us; speedup 1.0000x reference)
//
#include <hip/hip_runtime.h>

#define B_    16384
#define NZ_   64
#define ND_   8
#define SDIM_ 128
#define H_    512
#define CAP_  2320          // per-domain rowmap capacity (29 tiles x 80)
#define NTB_  29            // branch tiles/domain -> grid 232 <= 256

typedef _Float16 f16;
typedef __attribute__((ext_vector_type(4))) _Float16 half4;
typedef __attribute__((ext_vector_type(8))) _Float16 half8;
typedef __attribute__((ext_vector_type(4))) float floatx4;

#define VMCNT4 asm volatile("s_waitcnt vmcnt(4)" ::: "memory")
#define VMCNT1 asm volatile("s_waitcnt vmcnt(1)" ::: "memory")
#define VMCNT0 asm volatile("s_waitcnt vmcnt(0)" ::: "memory")
#define LGKM0  asm volatile("s_waitcnt lgkmcnt(0)" ::: "memory")

__device__ __forceinline__ void gload16(const void* gp, void* lp) {
    void* g = const_cast<void*>(gp);
    __builtin_amdgcn_global_load_lds(
        (__attribute__((address_space(1))) void*)g,
        (__attribute__((address_space(3))) void*)lp, 16, 0, 0);
}

// trunk swizzle: bits 4-6 ^= (row>>1)&7
__device__ __forceinline__ int pswz_t(int row, int colbyte) {
    return (row * 1024 + colbyte) ^ (((row >> 1) & 7) << 4);
}
// branch swizzle: bits 4-6 ^= row&7
__device__ __forceinline__ int pswz_b(int row, int colbyte) {
    return (row * 1024 + colbyte) ^ ((row & 7) << 4);
}

// ---------------- weight pack: [*,K,N] f32 -> fragment-tiled f16 ----------------
// NT=true: non-temporal (single-use stream; protects L2-resident trunk weights
// during mega's staggered trunk||transpose phase overlap).
template<bool NT>
__device__ __forceinline__ void tr_mat(float (*tb)[33], const float* __restrict__ s,
                                       f16* __restrict__ dd, int K, int N, int tl,
                                       int tid) {
    const int ntk = K >> 5;
    const int per = ntk * (N >> 5);
    const int bt  = tl / per;
    const int w   = tl - bt * per;
    s  += (size_t)bt * K * N;
    dd += (size_t)bt * K * N;
    const int k0 = (w % ntk) << 5, n0 = (w / ntk) << 5;
    {
        const int nn = tid & 31, k4 = tid >> 5;
        #pragma unroll
        for (int p = 0; p < 4; p++) {
            const float* sp = &s[(size_t)(k0 + k4 + p * 8) * N + n0 + nn];
            tb[k4 + p * 8][nn] = NT ? __builtin_nontemporal_load(sp) : *sp;
        }
    }
    __syncthreads();
    {
        const int sub = tid >> 7, r = tid & 127;
        const int lane = r >> 1, jp = (r & 1) * 4;
        const int kb = lane >> 4, l15 = lane & 15;
        const size_t base = ((size_t)((n0 >> 4) + sub) * (K >> 5) + (k0 >> 5)) * 512
                          + lane * 8 + jp;
        half4 h;
        #pragma unroll
        for (int jj = 0; jj < 4; jj++)
            h[jj] = (f16)tb[kb * 8 + jp + jj][sub * 16 + l15];
        if (NT) __builtin_nontemporal_store(h, (half4*)(dd + base));
        else    *(half4*)(dd + base) = h;
    }
}

// ---- W-weights (trunk needs these immediately) + cnt zeroing ----
__global__ __launch_bounds__(256) void tr_w_k(
    const float* W0, const float* W1, const float* W2, const float* W3,
    f16* W0t, f16* W1t, f16* W2t, f16* W3t, int* cnt)
{
    __shared__ float tb[32][33];
    if (blockIdx.x == 0 && threadIdx.x < ND_) cnt[threadIdx.x] = 0;
    int tl = blockIdx.x;
    if (tl < 32)   { tr_mat<false>(tb, W0, W0t, 64, 512, tl, threadIdx.x); return; }  tl -= 32;
    if (tl < 256)  { tr_mat<false>(tb, W1, W1t, 512, 512, tl, threadIdx.x); return; } tl -= 256;
    if (tl < 256)  { tr_mat<false>(tb, W2, W2t, 512, 512, tl, threadIdx.x); return; } tl -= 256;
    tr_mat<false>(tb, W3, W3t, 512, 512, tl, threadIdx.x);
}

// ================= TRUNK layer (r12, unchanged) =================
template<int MFRAG, int NFRAG, int KT, int NFN, int KTN, int SB, bool RELU>
__device__ __forceinline__ void layer_t(
    char* lds, const half8* __restrict__ wp, const half8* __restrict__ wpn,
    const float* __restrict__ bias, half8 (&b)[3][4])
{
    const int t = threadIdx.x;
    const int lane = t & 63, wid = t >> 6;
    const int l15 = lane & 15, kb = lane >> 4;

    int baseA[MFRAG];
    #pragma unroll
    for (int m = 0; m < MFRAG; m++)
        baseA[m] = (((m * 16 + l15) * 1024) + kb * 16) ^ (((l15 >> 1) & 7) << 4);

    half8 a[2][MFRAG];
    #pragma unroll
    for (int m = 0; m < MFRAG; m++) a[0][m] = *(const half8*)(lds + baseA[m]);

    floatx4 acc[MFRAG][NFRAG] = {};

    #pragma unroll
    for (int kt = 0; kt < KT; kt++) {
        const int cur = kt & 1;
        if (kt + 1 < KT) {
            #pragma unroll
            for (int m = 0; m < MFRAG; m++)
                a[cur ^ 1][m] = *(const half8*)(lds + (baseA[m] ^ ((kt + 1) << 6)));
        }
        if (kt + 2 < KT) {
            #pragma unroll
            for (int n = 0; n < NFRAG; n++)
                b[(SB + kt + 2) % 3][n] = wp[((wid * NFRAG + n) * KT + kt + 2) * 64 + lane];
        } else if constexpr (NFN > 0) {
            const int s2 = kt + 2 - KT;
            #pragma unroll
            for (int n = 0; n < NFN; n++)
                b[(SB + kt + 2) % 3][n] = wpn[((wid * NFN + n) * KTN + s2) * 64 + lane];
        }
        __builtin_amdgcn_s_setprio(1);
        #pragma unroll
        for (int m = 0; m < MFRAG; m++)
            #pragma unroll
            for (int n = 0; n < NFRAG; n++)
                acc[m][n] = __builtin_amdgcn_mfma_f32_16x16x32_f16(
                    a[cur][m], b[(SB + kt) % 3][n], acc[m][n], 0, 0, 0);
        __builtin_amdgcn_s_setprio(0);
    }

    __syncthreads();

    #pragma unroll
    for (int n = 0; n < NFRAG; n++) {
        const int col = wid * (NFRAG * 16) + n * 16 + l15;
        const float bb = bias[col];
        #pragma unroll
        for (int m = 0; m < MFRAG; m++) {
            #pragma unroll
            for (int e = 0; e < 4; e++) {
                const int row = m * 16 + kb * 4 + e;
                float v = acc[m][n][e] + bb;
                if constexpr (RELU) v = fmaxf(v, 0.0f);
                *(f16*)(lds + pswz_t(row, col * 2)) = (f16)v;
            }
        }
    }
    __syncthreads();
}

// ===== MEGA: 256 blocks, sequential phases per block (no CU sharing) =====
__global__ __launch_bounds__(512) void mega_k(
    const float* __restrict__ z,
    const f16* __restrict__ W0p, const float* __restrict__ b0,
    const f16* __restrict__ W1p, const float* __restrict__ b1,
    const f16* __restrict__ W2p, const float* __restrict__ b2,
    const f16* __restrict__ W3p, const float* __restrict__ b3,
    f16* __restrict__ hT,
    const float* U1, const float* U2, const float* U3, const float* Uo,
    f16* U1t, f16* U2t, f16* U3t, f16* Uot,
    const int* __restrict__ y, int* __restrict__ cnt, int* __restrict__ rowmap)
{
    extern __shared__ char lds[];
    const int bid = blockIdx.x;
    const int t = threadIdx.x;

    // ---------------- phase 1: trunk tile ----------------
    {
        const int row0 = bid * 64;
        const int lane = t & 63, wid = t >> 6;

        const half8* w0 = (const half8*)W0p;
        const half8* w1 = (const half8*)W1p;
        const half8* w2 = (const half8*)W2p;
        const half8* w3 = (const half8*)W3p;

        half8 b[3][4];
        #pragma unroll
        for (int s = 0; s < 2; s++)
            #pragma unroll
            for (int n = 0; n < 4; n++)
                b[s][n] = w0[((wid * 4 + n) * 2 + s) * 64 + lane];

        {
            const int r = t >> 3, c = (t & 7) * 8;
            const floatx4 v0 = __builtin_nontemporal_load(
                (const floatx4*)(z + (size_t)(row0 + r) * NZ_ + c));
            const floatx4 v1 = __builtin_nontemporal_load(
                (const floatx4*)(z + (size_t)(row0 + r) * NZ_ + c + 4));
            half8 h = { (f16)v0.x, (f16)v0.y, (f16)v0.z, (f16)v0.w,
                        (f16)v1.x, (f16)v1.y, (f16)v1.z, (f16)v1.w };
            *(half8*)(lds + pswz_t(r, c * 2)) = h;
        }
        __syncthreads();

        layer_t<4, 4, 2,  4, 16, 0, true>(lds, w0, w1, b0, b);
        layer_t<4, 4, 16, 4, 16, 2, true>(lds, w1, w2, b1, b);
        layer_t<4, 4, 16, 4, 16, 0, true>(lds, w2, w3, b2, b);
        layer_t<4, 4, 16, 0, 16, 1, true>(lds, w3, w3, b3, b);

        {
            const int r = t >> 3;
            #pragma unroll
            for (int p = 0; p < 8; p++) {
                const int c16 = (t & 7) + p * 8;
                half8 h = *(const half8*)(lds + pswz_t(r, c16 * 16));
                *(half8*)(hT + (size_t)(row0 + r) * H_ + c16 * 8) = h;
            }
        }
    }
    __syncthreads();   // LDS reuse boundary

    // -------- phase 2: 26 U-transpose tiles (non-temporal, single-use stream) --------
    {
        const int sub = t >> 8;          // two 256-thread halves, one tile each
        const int tid = t & 255;
        float (*tb)[33] = (float(*)[33])(lds + sub * 4352);
        #pragma unroll 1
        for (int it = 0; it < 13; it++) {
            int tl = bid * 26 + it * 2 + sub;     // 256*26 = 6656 tiles exactly
            if (tl < 2048)      tr_mat<true>(tb, U1, U1t, 512, 512, tl, tid);
            else if (tl < 4096) tr_mat<true>(tb, U2, U2t, 512, 512, tl - 2048, tid);
            else if (tl < 6144) tr_mat<true>(tb, U3, U3t, 512, 512, tl - 4096, tid);
            else                tr_mat<true>(tb, Uo, Uot, 512, 128, tl - 6144, tid);
            __syncthreads();             // both halves done before tb reuse
        }
    }

    // ---------------- phase 3: sort (blocks 0..31) ----------------
    if (bid < 32) {
        int* h     = (int*)lds;
        int* basep = h + 8;
        if (t < ND_) h[t] = 0;
        __syncthreads();
        const int b = bid * 512 + t;
        const int d = y[b];
        const int r = atomicAdd(&h[d], 1);
        __syncthreads();
        if (t < ND_) basep[t] = atomicAdd(&cnt[t], h[t]);
        __syncthreads();
        rowmap[d * CAP_ + basep[d] + r] = b;
    }
}

// ================= BRANCH (r14, unchanged: LDS-staged B + non-temporal) =================
template<int MFRAG, int NFRAG, int KT, bool RELU, bool TOPANEL>
__device__ __forceinline__ void layer_c(
    char* lds, char* ldsB, const f16* __restrict__ Wp, const float* __restrict__ bias,
    float* __restrict__ outf, const int* __restrict__ rmt, int vend)
{
    const int t = threadIdx.x;
    const int lane = t & 63, wid = t >> 6;
    const int l15 = lane & 15, kb = lane >> 4;
    const int swz = (l15 & 7) << 4;
    constexpr int BUFSZ = 8 * NFRAG * 1024;

    int baseA[MFRAG];
    #pragma unroll
    for (int m = 0; m < MFRAG; m++)
        baseA[m] = (((m * 16 + l15) * 1024) + kb * 16) ^ swz;

    char* chunk = ldsB + wid * (NFRAG * 1024);
    const f16* gw = Wp + (size_t)wid * NFRAG * KT * 512 + lane * 8;

    auto stage = [&](int s) {
        #pragma unroll
        for (int n = 0; n < NFRAG; n++)
            gload16(gw + ((size_t)n * KT + s) * 512,
                    chunk + (s & 1) * BUFSZ + n * 1024);
    };
    auto readB = [&](int s, half8 (&br)[NFRAG]) {
        #pragma unroll
        for (int n = 0; n < NFRAG; n++)
            br[n] = *(const half8*)(chunk + (s & 1) * BUFSZ + n * 1024 + lane * 16);
    };

    half8 a[2][MFRAG], br[2][NFRAG];
    floatx4 acc[MFRAG][NFRAG] = {};

    stage(0); stage(1);
    if constexpr (NFRAG == 4) VMCNT4; else VMCNT1;
    readB(0, br[0]);
    #pragma unroll
    for (int m = 0; m < MFRAG; m++) a[0][m] = *(const half8*)(lds + baseA[m]);

    #pragma unroll
    for (int kt = 0; kt < KT; kt++) {
        const int cur = kt & 1, nxt = cur ^ 1;
        __builtin_amdgcn_s_setprio(1);
        #pragma unroll
        for (int m = 0; m < MFRAG; m++)
            #pragma unroll
            for (int n = 0; n < NFRAG; n++)
                acc[m][n] = __builtin_amdgcn_mfma_f32_16x16x32_f16(
                    a[cur][m], br[cur][n], acc[m][n], 0, 0, 0);
        __builtin_amdgcn_s_setprio(0);
        if (kt + 2 < KT) {
            LGKM0;
            stage(kt + 2);
        }
        if (kt + 1 < KT) {
            if (kt + 2 < KT) { if constexpr (NFRAG == 4) VMCNT4; else VMCNT1; }
            else             { VMCNT0; }
            readB(kt + 1, br[nxt]);
            #pragma unroll
            for (int m = 0; m < MFRAG; m++)
                a[nxt][m] = *(const half8*)(lds + (baseA[m] ^ ((kt + 1) << 6)));
        }
    }

    __syncthreads();

    #pragma unroll
    for (int n = 0; n < NFRAG; n++) {
        const int col = wid * (NFRAG * 16) + n * 16 + l15;
        const float bb = bias[col];
        #pragma unroll
        for (int m = 0; m < MFRAG; m++) {
            #pragma unroll
            for (int e = 0; e < 4; e++) {
                const int row = m * 16 + kb * 4 + e;
                float v = acc[m][n][e] + bb;
                if constexpr (RELU) v = fmaxf(v, 0.0f);
                if constexpr (TOPANEL) {
                    *(f16*)(lds + pswz_b(row, col * 2)) = (f16)v;
                } else {
                    if (row < vend)
                        __builtin_nontemporal_store(v, &outf[(size_t)rmt[row] * SDIM_ + col]);
                }
            }
        }
    }
    if constexpr (TOPANEL) __syncthreads();
}

__global__ __launch_bounds__(512, 1) void branch_k(
    const f16* __restrict__ hT,
    const f16* __restrict__ U1p, const float* __restrict__ c1,
    const f16* __restrict__ U2p, const float* __restrict__ c2,
    const f16* __restrict__ U3p, const float* __restrict__ c3,
    const f16* __restrict__ Uop, const float* __restrict__ co,
    const int* __restrict__ cnt, const int* __restrict__ rowmap,
    float* __restrict__ out)
{
    extern __shared__ char lds[];
    char* ldsB = lds + 80 * 1024;
    const int d = blockIdx.x & 7, i = blockIdx.x >> 3;
    const int c = cnt[d];
    if (i * 80 >= c) return;
    const int vend = c - i * 80;
    const int* rmt = rowmap + d * CAP_ + i * 80;
    const int t = threadIdx.x;

    #pragma unroll
    for (int p = 0; p < 10; p++) {
        const int r   = p * 8 + (t >> 6);
        const int rr  = (r < vend) ? r : (vend - 1);
        const int c16 = t & 63;
        const int src = rmt[rr];
        half8 h = __builtin_nontemporal_load((const half8*)(hT + (size_t)src * H_ + c16 * 8));
        *(half8*)(lds + pswz_b(r, c16 * 16)) = h;
    }
    __syncthreads();

    const f16* u1 = U1p + (size_t)d * H_ * H_;
    const f16* u2 = U2p + (size_t)d * H_ * H_;
    const f16* u3 = U3p + (size_t)d * H_ * H_;
    const f16* uo = Uop + (size_t)d * H_ * SDIM_;

    layer_c<5, 4, 16, true,  true >(lds, ldsB, u1, c1 + d * H_,    nullptr, nullptr, 0);
    layer_c<5, 4, 16, true,  true >(lds, ldsB, u2, c2 + d * H_,    nullptr, nullptr, 0);
    layer_c<5, 4, 16, true,  true >(lds, ldsB, u3, c3 + d * H_,    nullptr, nullptr, 0);
    layer_c<5, 1, 16, false, false>(lds, ldsB, uo, co + d * SDIM_, out, rmt, vend);
}

// ---------------- host ----------------
extern "C" void kernel_launch(void* const* d_in, const int* in_sizes, int n_in,
                              void* d_out, int out_size, void* d_ws, size_t ws_size,
                              hipStream_t stream)
{
    const float* z  = (const float*)d_in[0];
    const int*   y  = (const int*)d_in[1];
    const float* W0 = (const float*)d_in[2];
    const float* b0 = (const float*)d_in[3];
    const float* W1 = (const float*)d_in[4];
    const float* b1 = (const float*)d_in[5];
    const float* W2 = (const float*)d_in[6];
    const float* b2 = (const float*)d_in[7];
    const float* W3 = (const float*)d_in[8];
    const float* b3 = (const float*)d_in[9];
    const float* U1 = (const float*)d_in[10];
    const float* c1 = (const float*)d_in[11];
    const float* U2 = (const float*)d_in[12];
    const float* c2 = (const float*)d_in[13];
    const float* U3 = (const float*)d_in[14];
    const float* c3 = (const float*)d_in[15];
    const float* Uo = (const float*)d_in[16];
    const float* co = (const float*)d_in[17];
    float* out = (float*)d_out;

    char* p = (char*)d_ws;
    auto take = [&](size_t nbytes) { char* r = p; p += (nbytes + 255) & ~(size_t)255; return r; };
    int* cnt    = (int*)take(ND_ * 4);
    int* rowmap = (int*)take((size_t)ND_ * CAP_ * 4);
    f16* W0t = (f16*)take((size_t)H_ * NZ_ * 2);
    f16* W1t = (f16*)take((size_t)H_ * H_ * 2);
    f16* W2t = (f16*)take((size_t)H_ * H_ * 2);
    f16* W3t = (f16*)take((size_t)H_ * H_ * 2);
    f16* U1t = (f16*)take((size_t)ND_ * H_ * H_ * 2);
    f16* U2t = (f16*)take((size_t)ND_ * H_ * H_ * 2);
    f16* U3t = (f16*)take((size_t)ND_ * H_ * H_ * 2);
    f16* Uot = (f16*)take((size_t)ND_ * SDIM_ * H_ * 2);
    f16* hT  = (f16*)take((size_t)B_ * H_ * 2);

    hipFuncSetAttribute((const void*)mega_k,   hipFuncAttributeMaxDynamicSharedMemorySize, 64 * 1024);
    hipFuncSetAttribute((const void*)branch_k, hipFuncAttributeMaxDynamicSharedMemorySize, 144 * 1024);

    tr_w_k<<<dim3(800), dim3(256), 0, stream>>>(W0, W1, W2, W3, W0t, W1t, W2t, W3t, cnt);

    mega_k<<<dim3(256), dim3(512), 64 * 1024, stream>>>(
        z, W0t, b0, W1t, b1, W2t, b2, W3t, b3, hT,
        U1, U2, U3, Uo, U1t, U2t, U3t, Uot,
        y, cnt, rowmap);

    branch_k<<<dim3(8 * NTB_), dim3(512), 144 * 1024, stream>>>(
        hT, U1t, c1, U2t, c2, U3t, c3, Uot, co, cnt, rowmap, out);
}

// Round 18
// 89.208 us; speedup vs baseline: 1.0296x; 1.0296x over previous
//
#include <hip/hip_runtime.h>

#define B_    16384
#define NZ_   64
#define ND_   8
#define SDIM_ 128
#define H_    512
#define CAP_  2320          // per-domain rowmap capacity (29 tiles x 80)
#define NTB_  29            // branch tiles/domain -> grid 232 <= 256

typedef _Float16 f16;
typedef __attribute__((ext_vector_type(4))) _Float16 half4;
typedef __attribute__((ext_vector_type(8))) _Float16 half8;
typedef __attribute__((ext_vector_type(4))) float floatx4;

#define VMCNT4 asm volatile("s_waitcnt vmcnt(4)" ::: "memory")
#define VMCNT1 asm volatile("s_waitcnt vmcnt(1)" ::: "memory")
#define VMCNT0 asm volatile("s_waitcnt vmcnt(0)" ::: "memory")
#define LGKM0  asm volatile("s_waitcnt lgkmcnt(0)" ::: "memory")

__device__ __forceinline__ void gload16(const void* gp, void* lp) {
    void* g = const_cast<void*>(gp);
    __builtin_amdgcn_global_load_lds(
        (__attribute__((address_space(1))) void*)g,
        (__attribute__((address_space(3))) void*)lp, 16, 0, 0);
}

// trunk swizzle: bits 4-6 ^= (row>>1)&7
__device__ __forceinline__ int pswz_t(int row, int colbyte) {
    return (row * 1024 + colbyte) ^ (((row >> 1) & 7) << 4);
}
// branch swizzle: bits 4-6 ^= row&7
__device__ __forceinline__ int pswz_b(int row, int colbyte) {
    return (row * 1024 + colbyte) ^ ((row & 7) << 4);
}

// ---------------- weight pack: [*,K,N] f32 -> fragment-tiled f16 ----------------
// NTL: non-temporal LOAD of the f32 source (single-use stream; protects the
// L2-resident trunk weights during mega's phase overlap).  Stores stay NORMAL:
// the packed weights are immediately re-read 29x by branch_k — r17 proved an
// NT store here breaks the producer->consumer cache handoff (+6.7 us).
template<bool NTL>
__device__ __forceinline__ void tr_mat(float (*tb)[33], const float* __restrict__ s,
                                       f16* __restrict__ dd, int K, int N, int tl,
                                       int tid) {
    const int ntk = K >> 5;
    const int per = ntk * (N >> 5);
    const int bt  = tl / per;
    const int w   = tl - bt * per;
    s  += (size_t)bt * K * N;
    dd += (size_t)bt * K * N;
    const int k0 = (w % ntk) << 5, n0 = (w / ntk) << 5;
    {
        const int nn = tid & 31, k4 = tid >> 5;
        #pragma unroll
        for (int p = 0; p < 4; p++) {
            const float* sp = &s[(size_t)(k0 + k4 + p * 8) * N + n0 + nn];
            tb[k4 + p * 8][nn] = NTL ? __builtin_nontemporal_load(sp) : *sp;
        }
    }
    __syncthreads();
    {
        const int sub = tid >> 7, r = tid & 127;
        const int lane = r >> 1, jp = (r & 1) * 4;
        const int kb = lane >> 4, l15 = lane & 15;
        const size_t base = ((size_t)((n0 >> 4) + sub) * (K >> 5) + (k0 >> 5)) * 512
                          + lane * 8 + jp;
        half4 h;
        #pragma unroll
        for (int jj = 0; jj < 4; jj++)
            h[jj] = (f16)tb[kb * 8 + jp + jj][sub * 16 + l15];
        *(half4*)(dd + base) = h;
    }
}

// ---- W-weights (trunk needs these immediately) + cnt zeroing ----
__global__ __launch_bounds__(256) void tr_w_k(
    const float* W0, const float* W1, const float* W2, const float* W3,
    f16* W0t, f16* W1t, f16* W2t, f16* W3t, int* cnt)
{
    __shared__ float tb[32][33];
    if (blockIdx.x == 0 && threadIdx.x < ND_) cnt[threadIdx.x] = 0;
    int tl = blockIdx.x;
    if (tl < 32)   { tr_mat<false>(tb, W0, W0t, 64, 512, tl, threadIdx.x); return; }  tl -= 32;
    if (tl < 256)  { tr_mat<false>(tb, W1, W1t, 512, 512, tl, threadIdx.x); return; } tl -= 256;
    if (tl < 256)  { tr_mat<false>(tb, W2, W2t, 512, 512, tl, threadIdx.x); return; } tl -= 256;
    tr_mat<false>(tb, W3, W3t, 512, 512, tl, threadIdx.x);
}

// ================= TRUNK layer (r12, unchanged) =================
template<int MFRAG, int NFRAG, int KT, int NFN, int KTN, int SB, bool RELU>
__device__ __forceinline__ void layer_t(
    char* lds, const half8* __restrict__ wp, const half8* __restrict__ wpn,
    const float* __restrict__ bias, half8 (&b)[3][4])
{
    const int t = threadIdx.x;
    const int lane = t & 63, wid = t >> 6;
    const int l15 = lane & 15, kb = lane >> 4;

    int baseA[MFRAG];
    #pragma unroll
    for (int m = 0; m < MFRAG; m++)
        baseA[m] = (((m * 16 + l15) * 1024) + kb * 16) ^ (((l15 >> 1) & 7) << 4);

    half8 a[2][MFRAG];
    #pragma unroll
    for (int m = 0; m < MFRAG; m++) a[0][m] = *(const half8*)(lds + baseA[m]);

    floatx4 acc[MFRAG][NFRAG] = {};

    #pragma unroll
    for (int kt = 0; kt < KT; kt++) {
        const int cur = kt & 1;
        if (kt + 1 < KT) {
            #pragma unroll
            for (int m = 0; m < MFRAG; m++)
                a[cur ^ 1][m] = *(const half8*)(lds + (baseA[m] ^ ((kt + 1) << 6)));
        }
        if (kt + 2 < KT) {
            #pragma unroll
            for (int n = 0; n < NFRAG; n++)
                b[(SB + kt + 2) % 3][n] = wp[((wid * NFRAG + n) * KT + kt + 2) * 64 + lane];
        } else if constexpr (NFN > 0) {
            const int s2 = kt + 2 - KT;
            #pragma unroll
            for (int n = 0; n < NFN; n++)
                b[(SB + kt + 2) % 3][n] = wpn[((wid * NFN + n) * KTN + s2) * 64 + lane];
        }
        __builtin_amdgcn_s_setprio(1);
        #pragma unroll
        for (int m = 0; m < MFRAG; m++)
            #pragma unroll
            for (int n = 0; n < NFRAG; n++)
                acc[m][n] = __builtin_amdgcn_mfma_f32_16x16x32_f16(
                    a[cur][m], b[(SB + kt) % 3][n], acc[m][n], 0, 0, 0);
        __builtin_amdgcn_s_setprio(0);
    }

    __syncthreads();

    #pragma unroll
    for (int n = 0; n < NFRAG; n++) {
        const int col = wid * (NFRAG * 16) + n * 16 + l15;
        const float bb = bias[col];
        #pragma unroll
        for (int m = 0; m < MFRAG; m++) {
            #pragma unroll
            for (int e = 0; e < 4; e++) {
                const int row = m * 16 + kb * 4 + e;
                float v = acc[m][n][e] + bb;
                if constexpr (RELU) v = fmaxf(v, 0.0f);
                *(f16*)(lds + pswz_t(row, col * 2)) = (f16)v;
            }
        }
    }
    __syncthreads();
}

// ===== MEGA: 256 blocks, sequential phases per block (no CU sharing) =====
__global__ __launch_bounds__(512) void mega_k(
    const float* __restrict__ z,
    const f16* __restrict__ W0p, const float* __restrict__ b0,
    const f16* __restrict__ W1p, const float* __restrict__ b1,
    const f16* __restrict__ W2p, const float* __restrict__ b2,
    const f16* __restrict__ W3p, const float* __restrict__ b3,
    f16* __restrict__ hT,
    const float* U1, const float* U2, const float* U3, const float* Uo,
    f16* U1t, f16* U2t, f16* U3t, f16* Uot,
    const int* __restrict__ y, int* __restrict__ cnt, int* __restrict__ rowmap)
{
    extern __shared__ char lds[];
    const int bid = blockIdx.x;
    const int t = threadIdx.x;

    // ---------------- phase 1: trunk tile ----------------
    {
        const int row0 = bid * 64;
        const int lane = t & 63, wid = t >> 6;

        const half8* w0 = (const half8*)W0p;
        const half8* w1 = (const half8*)W1p;
        const half8* w2 = (const half8*)W2p;
        const half8* w3 = (const half8*)W3p;

        half8 b[3][4];
        #pragma unroll
        for (int s = 0; s < 2; s++)
            #pragma unroll
            for (int n = 0; n < 4; n++)
                b[s][n] = w0[((wid * 4 + n) * 2 + s) * 64 + lane];

        {
            const int r = t >> 3, c = (t & 7) * 8;
            const floatx4 v0 = __builtin_nontemporal_load(
                (const floatx4*)(z + (size_t)(row0 + r) * NZ_ + c));
            const floatx4 v1 = __builtin_nontemporal_load(
                (const floatx4*)(z + (size_t)(row0 + r) * NZ_ + c + 4));
            half8 h = { (f16)v0.x, (f16)v0.y, (f16)v0.z, (f16)v0.w,
                        (f16)v1.x, (f16)v1.y, (f16)v1.z, (f16)v1.w };
            *(half8*)(lds + pswz_t(r, c * 2)) = h;
        }
        __syncthreads();

        layer_t<4, 4, 2,  4, 16, 0, true>(lds, w0, w1, b0, b);
        layer_t<4, 4, 16, 4, 16, 2, true>(lds, w1, w2, b1, b);
        layer_t<4, 4, 16, 4, 16, 0, true>(lds, w2, w3, b2, b);
        layer_t<4, 4, 16, 0, 16, 1, true>(lds, w3, w3, b3, b);

        {
            const int r = t >> 3;
            #pragma unroll
            for (int p = 0; p < 8; p++) {
                const int c16 = (t & 7) + p * 8;
                half8 h = *(const half8*)(lds + pswz_t(r, c16 * 16));
                *(half8*)(hT + (size_t)(row0 + r) * H_ + c16 * 8) = h;
            }
        }
    }
    __syncthreads();   // LDS reuse boundary

    // -------- phase 2: 26 U-transpose tiles (NT loads; NORMAL stores) --------
    {
        const int sub = t >> 8;          // two 256-thread halves, one tile each
        const int tid = t & 255;
        float (*tb)[33] = (float(*)[33])(lds + sub * 4352);
        #pragma unroll 1
        for (int it = 0; it < 13; it++) {
            int tl = bid * 26 + it * 2 + sub;     // 256*26 = 6656 tiles exactly
            if (tl < 2048)      tr_mat<true>(tb, U1, U1t, 512, 512, tl, tid);
            else if (tl < 4096) tr_mat<true>(tb, U2, U2t, 512, 512, tl - 2048, tid);
            else if (tl < 6144) tr_mat<true>(tb, U3, U3t, 512, 512, tl - 4096, tid);
            else                tr_mat<true>(tb, Uo, Uot, 512, 128, tl - 6144, tid);
            __syncthreads();             // both halves done before tb reuse
        }
    }

    // ---------------- phase 3: sort (blocks 0..31) ----------------
    if (bid < 32) {
        int* h     = (int*)lds;
        int* basep = h + 8;
        if (t < ND_) h[t] = 0;
        __syncthreads();
        const int b = bid * 512 + t;
        const int d = y[b];
        const int r = atomicAdd(&h[d], 1);
        __syncthreads();
        if (t < ND_) basep[t] = atomicAdd(&cnt[t], h[t]);
        __syncthreads();
        rowmap[d * CAP_ + basep[d] + r] = b;
    }
}

// ================= BRANCH (r14, unchanged: LDS-staged B + non-temporal hT/out) =================
template<int MFRAG, int NFRAG, int KT, bool RELU, bool TOPANEL>
__device__ __forceinline__ void layer_c(
    char* lds, char* ldsB, const f16* __restrict__ Wp, const float* __restrict__ bias,
    float* __restrict__ outf, const int* __restrict__ rmt, int vend)
{
    const int t = threadIdx.x;
    const int lane = t & 63, wid = t >> 6;
    const int l15 = lane & 15, kb = lane >> 4;
    const int swz = (l15 & 7) << 4;
    constexpr int BUFSZ = 8 * NFRAG * 1024;

    int baseA[MFRAG];
    #pragma unroll
    for (int m = 0; m < MFRAG; m++)
        baseA[m] = (((m * 16 + l15) * 1024) + kb * 16) ^ swz;

    char* chunk = ldsB + wid * (NFRAG * 1024);
    const f16* gw = Wp + (size_t)wid * NFRAG * KT * 512 + lane * 8;

    auto stage = [&](int s) {
        #pragma unroll
        for (int n = 0; n < NFRAG; n++)
            gload16(gw + ((size_t)n * KT + s) * 512,
                    chunk + (s & 1) * BUFSZ + n * 1024);
    };
    auto readB = [&](int s, half8 (&br)[NFRAG]) {
        #pragma unroll
        for (int n = 0; n < NFRAG; n++)
            br[n] = *(const half8*)(chunk + (s & 1) * BUFSZ + n * 1024 + lane * 16);
    };

    half8 a[2][MFRAG], br[2][NFRAG];
    floatx4 acc[MFRAG][NFRAG] = {};

    stage(0); stage(1);
    if constexpr (NFRAG == 4) VMCNT4; else VMCNT1;
    readB(0, br[0]);
    #pragma unroll
    for (int m = 0; m < MFRAG; m++) a[0][m] = *(const half8*)(lds + baseA[m]);

    #pragma unroll
    for (int kt = 0; kt < KT; kt++) {
        const int cur = kt & 1, nxt = cur ^ 1;
        __builtin_amdgcn_s_setprio(1);
        #pragma unroll
        for (int m = 0; m < MFRAG; m++)
            #pragma unroll
            for (int n = 0; n < NFRAG; n++)
                acc[m][n] = __builtin_amdgcn_mfma_f32_16x16x32_f16(
                    a[cur][m], br[cur][n], acc[m][n], 0, 0, 0);
        __builtin_amdgcn_s_setprio(0);
        if (kt + 2 < KT) {
            LGKM0;
            stage(kt + 2);
        }
        if (kt + 1 < KT) {
            if (kt + 2 < KT) { if constexpr (NFRAG == 4) VMCNT4; else VMCNT1; }
            else             { VMCNT0; }
            readB(kt + 1, br[nxt]);
            #pragma unroll
            for (int m = 0; m < MFRAG; m++)
                a[nxt][m] = *(const half8*)(lds + (baseA[m] ^ ((kt + 1) << 6)));
        }
    }

    __syncthreads();

    #pragma unroll
    for (int n = 0; n < NFRAG; n++) {
        const int col = wid * (NFRAG * 16) + n * 16 + l15;
        const float bb = bias[col];
        #pragma unroll
        for (int m = 0; m < MFRAG; m++) {
            #pragma unroll
            for (int e = 0; e < 4; e++) {
                const int row = m * 16 + kb * 4 + e;
                float v = acc[m][n][e] + bb;
                if constexpr (RELU) v = fmaxf(v, 0.0f);
                if constexpr (TOPANEL) {
                    *(f16*)(lds + pswz_b(row, col * 2)) = (f16)v;
                } else {
                    if (row < vend)
                        __builtin_nontemporal_store(v, &outf[(size_t)rmt[row] * SDIM_ + col]);
                }
            }
        }
    }
    if constexpr (TOPANEL) __syncthreads();
}

__global__ __launch_bounds__(512, 1) void branch_k(
    const f16* __restrict__ hT,
    const f16* __restrict__ U1p, const float* __restrict__ c1,
    const f16* __restrict__ U2p, const float* __restrict__ c2,
    const f16* __restrict__ U3p, const float* __restrict__ c3,
    const f16* __restrict__ Uop, const float* __restrict__ co,
    const int* __restrict__ cnt, const int* __restrict__ rowmap,
    float* __restrict__ out)
{
    extern __shared__ char lds[];
    char* ldsB = lds + 80 * 1024;
    const int d = blockIdx.x & 7, i = blockIdx.x >> 3;
    const int c = cnt[d];
    if (i * 80 >= c) return;
    const int vend = c - i * 80;
    const int* rmt = rowmap + d * CAP_ + i * 80;
    const int t = threadIdx.x;

    #pragma unroll
    for (int p = 0; p < 10; p++) {
        const int r   = p * 8 + (t >> 6);
        const int rr  = (r < vend) ? r : (vend - 1);
        const int c16 = t & 63;
        const int src = rmt[rr];
        half8 h = __builtin_nontemporal_load((const half8*)(hT + (size_t)src * H_ + c16 * 8));
        *(half8*)(lds + pswz_b(r, c16 * 16)) = h;
    }
    __syncthreads();

    const f16* u1 = U1p + (size_t)d * H_ * H_;
    const f16* u2 = U2p + (size_t)d * H_ * H_;
    const f16* u3 = U3p + (size_t)d * H_ * H_;
    const f16* uo = Uop + (size_t)d * H_ * SDIM_;

    layer_c<5, 4, 16, true,  true >(lds, ldsB, u1, c1 + d * H_,    nullptr, nullptr, 0);
    layer_c<5, 4, 16, true,  true >(lds, ldsB, u2, c2 + d * H_,    nullptr, nullptr, 0);
    layer_c<5, 4, 16, true,  true >(lds, ldsB, u3, c3 + d * H_,    nullptr, nullptr, 0);
    layer_c<5, 1, 16, false, false>(lds, ldsB, uo, co + d * SDIM_, out, rmt, vend);
}

// ---------------- host ----------------
extern "C" void kernel_launch(void* const* d_in, const int* in_sizes, int n_in,
                              void* d_out, int out_size, void* d_ws, size_t ws_size,
                              hipStream_t stream)
{
    const float* z  = (const float*)d_in[0];
    const int*   y  = (const int*)d_in[1];
    const float* W0 = (const float*)d_in[2];
    const float* b0 = (const float*)d_in[3];
    const float* W1 = (const float*)d_in[4];
    const float* b1 = (const float*)d_in[5];
    const float* W2 = (const float*)d_in[6];
    const float* b2 = (const float*)d_in[7];
    const float* W3 = (const float*)d_in[8];
    const float* b3 = (const float*)d_in[9];
    const float* U1 = (const float*)d_in[10];
    const float* c1 = (const float*)d_in[11];
    const float* U2 = (const float*)d_in[12];
    const float* c2 = (const float*)d_in[13];
    const float* U3 = (const float*)d_in[14];
    const float* c3 = (const float*)d_in[15];
    const float* Uo = (const float*)d_in[16];
    const float* co = (const float*)d_in[17];
    float* out = (float*)d_out;

    char* p = (char*)d_ws;
    auto take = [&](size_t nbytes) { char* r = p; p += (nbytes + 255) & ~(size_t)255; return r; };
    int* cnt    = (int*)take(ND_ * 4);
    int* rowmap = (int*)take((size_t)ND_ * CAP_ * 4);
    f16* W0t = (f16*)take((size_t)H_ * NZ_ * 2);
    f16* W1t = (f16*)take((size_t)H_ * H_ * 2);
    f16* W2t = (f16*)take((size_t)H_ * H_ * 2);
    f16* W3t = (f16*)take((size_t)H_ * H_ * 2);
    f16* U1t = (f16*)take((size_t)ND_ * H_ * H_ * 2);
    f16* U2t = (f16*)take((size_t)ND_ * H_ * H_ * 2);
    f16* U3t = (f16*)take((size_t)ND_ * H_ * H_ * 2);
    f16* Uot = (f16*)take((size_t)ND_ * SDIM_ * H_ * 2);
    f16* hT  = (f16*)take((size_t)B_ * H_ * 2);

    hipFuncSetAttribute((const void*)mega_k,   hipFuncAttributeMaxDynamicSharedMemorySize, 64 * 1024);
    hipFuncSetAttribute((const void*)branch_k, hipFuncAttributeMaxDynamicSharedMemorySize, 144 * 1024);

    tr_w_k<<<dim3(800), dim3(256), 0, stream>>>(W0, W1, W2, W3, W0t, W1t, W2t, W3t, cnt);

    mega_k<<<dim3(256), dim3(512), 64 * 1024, stream>>>(
        z, W0t, b0, W1t, b1, W2t, b2, W3t, b3, hT,
        U1, U2, U3, Uo, U1t, U2t, U3t, Uot,
        y, cnt, rowmap);

    branch_k<<<dim3(8 * NTB_), dim3(512), 144 * 1024, stream>>>(
        hT, U1t, c1, U2t, c2, U3t, c3, Uot, co, cnt, rowmap, out);
}

// Round 19
// 85.394 us; speedup vs baseline: 1.0755x; 1.0447x over previous
//
#include <hip/hip_runtime.h>

#define B_    16384
#define NZ_   64
#define ND_   8
#define SDIM_ 128
#define H_    512
#define CAP_  2320          // per-domain rowmap capacity (29 tiles x 80)
#define NTB_  29            // branch tiles/domain -> grid 232 <= 256

typedef _Float16 f16;
typedef __attribute__((ext_vector_type(4))) _Float16 half4;
typedef __attribute__((ext_vector_type(8))) _Float16 half8;
typedef __attribute__((ext_vector_type(4))) float floatx4;

#define VMCNT4 asm volatile("s_waitcnt vmcnt(4)" ::: "memory")
#define VMCNT1 asm volatile("s_waitcnt vmcnt(1)" ::: "memory")
#define VMCNT0 asm volatile("s_waitcnt vmcnt(0)" ::: "memory")
#define LGKM0  asm volatile("s_waitcnt lgkmcnt(0)" ::: "memory")

__device__ __forceinline__ void gload16(const void* gp, void* lp) {
    void* g = const_cast<void*>(gp);
    __builtin_amdgcn_global_load_lds(
        (__attribute__((address_space(1))) void*)g,
        (__attribute__((address_space(3))) void*)lp, 16, 0, 0);
}

// trunk swizzle: bits 4-6 ^= (row>>1)&7
__device__ __forceinline__ int pswz_t(int row, int colbyte) {
    return (row * 1024 + colbyte) ^ (((row >> 1) & 7) << 4);
}
// branch swizzle: bits 4-6 ^= row&7
__device__ __forceinline__ int pswz_b(int row, int colbyte) {
    return (row * 1024 + colbyte) ^ ((row & 7) << 4);
}

// ---------------- weight pack: [*,K,N] f32 -> fragment-tiled f16 ----------------
// Plain loads/stores: NT loads were null (r18), NT stores regressed (r17 —
// the packed weights are re-read 29x by branch_k; keep them cache-resident).
__device__ __forceinline__ void tr_mat(float (*tb)[33], const float* __restrict__ s,
                                       f16* __restrict__ dd, int K, int N, int tl,
                                       int tid) {
    const int ntk = K >> 5;
    const int per = ntk * (N >> 5);
    const int bt  = tl / per;
    const int w   = tl - bt * per;
    s  += (size_t)bt * K * N;
    dd += (size_t)bt * K * N;
    const int k0 = (w % ntk) << 5, n0 = (w / ntk) << 5;
    {
        const int nn = tid & 31, k4 = tid >> 5;
        #pragma unroll
        for (int p = 0; p < 4; p++)
            tb[k4 + p * 8][nn] = s[(size_t)(k0 + k4 + p * 8) * N + n0 + nn];
    }
    __syncthreads();
    {
        const int sub = tid >> 7, r = tid & 127;
        const int lane = r >> 1, jp = (r & 1) * 4;
        const int kb = lane >> 4, l15 = lane & 15;
        const size_t base = ((size_t)((n0 >> 4) + sub) * (K >> 5) + (k0 >> 5)) * 512
                          + lane * 8 + jp;
        half4 h;
        #pragma unroll
        for (int jj = 0; jj < 4; jj++)
            h[jj] = (f16)tb[kb * 8 + jp + jj][sub * 16 + l15];
        *(half4*)(dd + base) = h;
    }
}

// ---- W-weights (trunk needs these immediately) + cnt zeroing ----
__global__ __launch_bounds__(256) void tr_w_k(
    const float* W0, const float* W1, const float* W2, const float* W3,
    f16* W0t, f16* W1t, f16* W2t, f16* W3t, int* cnt)
{
    __shared__ float tb[32][33];
    if (blockIdx.x == 0 && threadIdx.x < ND_) cnt[threadIdx.x] = 0;
    int tl = blockIdx.x;
    if (tl < 32)   { tr_mat(tb, W0, W0t, 64, 512, tl, threadIdx.x); return; }  tl -= 32;
    if (tl < 256)  { tr_mat(tb, W1, W1t, 512, 512, tl, threadIdx.x); return; } tl -= 256;
    if (tl < 256)  { tr_mat(tb, W2, W2t, 512, 512, tl, threadIdx.x); return; } tl -= 256;
    tr_mat(tb, W3, W3t, 512, 512, tl, threadIdx.x);
}

// ================= TRUNK layer (r12, unchanged) =================
template<int MFRAG, int NFRAG, int KT, int NFN, int KTN, int SB, bool RELU>
__device__ __forceinline__ void layer_t(
    char* lds, const half8* __restrict__ wp, const half8* __restrict__ wpn,
    const float* __restrict__ bias, half8 (&b)[3][4])
{
    const int t = threadIdx.x;
    const int lane = t & 63, wid = t >> 6;
    const int l15 = lane & 15, kb = lane >> 4;

    int baseA[MFRAG];
    #pragma unroll
    for (int m = 0; m < MFRAG; m++)
        baseA[m] = (((m * 16 + l15) * 1024) + kb * 16) ^ (((l15 >> 1) & 7) << 4);

    half8 a[2][MFRAG];
    #pragma unroll
    for (int m = 0; m < MFRAG; m++) a[0][m] = *(const half8*)(lds + baseA[m]);

    floatx4 acc[MFRAG][NFRAG] = {};

    #pragma unroll
    for (int kt = 0; kt < KT; kt++) {
        const int cur = kt & 1;
        if (kt + 1 < KT) {
            #pragma unroll
            for (int m = 0; m < MFRAG; m++)
                a[cur ^ 1][m] = *(const half8*)(lds + (baseA[m] ^ ((kt + 1) << 6)));
        }
        if (kt + 2 < KT) {
            #pragma unroll
            for (int n = 0; n < NFRAG; n++)
                b[(SB + kt + 2) % 3][n] = wp[((wid * NFRAG + n) * KT + kt + 2) * 64 + lane];
        } else if constexpr (NFN > 0) {
            const int s2 = kt + 2 - KT;
            #pragma unroll
            for (int n = 0; n < NFN; n++)
                b[(SB + kt + 2) % 3][n] = wpn[((wid * NFN + n) * KTN + s2) * 64 + lane];
        }
        __builtin_amdgcn_s_setprio(1);
        #pragma unroll
        for (int m = 0; m < MFRAG; m++)
            #pragma unroll
            for (int n = 0; n < NFRAG; n++)
                acc[m][n] = __builtin_amdgcn_mfma_f32_16x16x32_f16(
                    a[cur][m], b[(SB + kt) % 3][n], acc[m][n], 0, 0, 0);
        __builtin_amdgcn_s_setprio(0);
    }

    __syncthreads();

    #pragma unroll
    for (int n = 0; n < NFRAG; n++) {
        const int col = wid * (NFRAG * 16) + n * 16 + l15;
        const float bb = bias[col];
        #pragma unroll
        for (int m = 0; m < MFRAG; m++) {
            #pragma unroll
            for (int e = 0; e < 4; e++) {
                const int row = m * 16 + kb * 4 + e;
                float v = acc[m][n][e] + bb;
                if constexpr (RELU) v = fmaxf(v, 0.0f);
                *(f16*)(lds + pswz_t(row, col * 2)) = (f16)v;
            }
        }
    }
    __syncthreads();
}

// ===== MEGA: 256 blocks, sequential phases per block (no CU sharing) =====
__global__ __launch_bounds__(512) void mega_k(
    const float* __restrict__ z,
    const f16* __restrict__ W0p, const float* __restrict__ b0,
    const f16* __restrict__ W1p, const float* __restrict__ b1,
    const f16* __restrict__ W2p, const float* __restrict__ b2,
    const f16* __restrict__ W3p, const float* __restrict__ b3,
    f16* __restrict__ hT,
    const float* U1, const float* U2, const float* U3, const float* Uo,
    f16* U1t, f16* U2t, f16* U3t, f16* Uot,
    const int* __restrict__ y, int* __restrict__ cnt, int* __restrict__ rowmap)
{
    extern __shared__ char lds[];
    const int bid = blockIdx.x;
    const int t = threadIdx.x;

    // ---------------- phase 1: trunk tile ----------------
    {
        const int row0 = bid * 64;
        const int lane = t & 63, wid = t >> 6;

        const half8* w0 = (const half8*)W0p;
        const half8* w1 = (const half8*)W1p;
        const half8* w2 = (const half8*)W2p;
        const half8* w3 = (const half8*)W3p;

        half8 b[3][4];
        #pragma unroll
        for (int s = 0; s < 2; s++)
            #pragma unroll
            for (int n = 0; n < 4; n++)
                b[s][n] = w0[((wid * 4 + n) * 2 + s) * 64 + lane];

        {
            const int r = t >> 3, c = (t & 7) * 8;
            const float4 v0 = *(const float4*)(z + (size_t)(row0 + r) * NZ_ + c);
            const float4 v1 = *(const float4*)(z + (size_t)(row0 + r) * NZ_ + c + 4);
            half8 h = { (f16)v0.x, (f16)v0.y, (f16)v0.z, (f16)v0.w,
                        (f16)v1.x, (f16)v1.y, (f16)v1.z, (f16)v1.w };
            *(half8*)(lds + pswz_t(r, c * 2)) = h;
        }
        __syncthreads();

        layer_t<4, 4, 2,  4, 16, 0, true>(lds, w0, w1, b0, b);
        layer_t<4, 4, 16, 4, 16, 2, true>(lds, w1, w2, b1, b);
        layer_t<4, 4, 16, 4, 16, 0, true>(lds, w2, w3, b2, b);
        layer_t<4, 4, 16, 0, 16, 1, true>(lds, w3, w3, b3, b);

        {
            const int r = t >> 3;
            #pragma unroll
            for (int p = 0; p < 8; p++) {
                const int c16 = (t & 7) + p * 8;
                half8 h = *(const half8*)(lds + pswz_t(r, c16 * 16));
                *(half8*)(hT + (size_t)(row0 + r) * H_ + c16 * 8) = h;
            }
        }
    }
    __syncthreads();   // LDS reuse boundary

    // -------- phase 2: 26 U-transpose tiles --------
    {
        const int sub = t >> 8;          // two 256-thread halves, one tile each
        const int tid = t & 255;
        float (*tb)[33] = (float(*)[33])(lds + sub * 4352);
        #pragma unroll 1
        for (int it = 0; it < 13; it++) {
            int tl = bid * 26 + it * 2 + sub;     // 256*26 = 6656 tiles exactly
            if (tl < 2048)      tr_mat(tb, U1, U1t, 512, 512, tl, tid);
            else if (tl < 4096) tr_mat(tb, U2, U2t, 512, 512, tl - 2048, tid);
            else if (tl < 6144) tr_mat(tb, U3, U3t, 512, 512, tl - 4096, tid);
            else                tr_mat(tb, Uo, Uot, 512, 128, tl - 6144, tid);
            __syncthreads();             // both halves done before tb reuse
        }
    }

    // ---------------- phase 3: sort (blocks 0..31) ----------------
    if (bid < 32) {
        int* h     = (int*)lds;
        int* basep = h + 8;
        if (t < ND_) h[t] = 0;
        __syncthreads();
        const int b = bid * 512 + t;
        const int d = y[b];
        const int r = atomicAdd(&h[d], 1);
        __syncthreads();
        if (t < ND_) basep[t] = atomicAdd(&cnt[t], h[t]);
        __syncthreads();
        rowmap[d * CAP_ + basep[d] + r] = b;
    }
}

// ================= BRANCH (r14: LDS-staged B + non-temporal hT/out) =================
template<int MFRAG, int NFRAG, int KT, bool RELU, bool TOPANEL>
__device__ __forceinline__ void layer_c(
    char* lds, char* ldsB, const f16* __restrict__ Wp, const float* __restrict__ bias,
    float* __restrict__ outf, const int* __restrict__ rmt, int vend)
{
    const int t = threadIdx.x;
    const int lane = t & 63, wid = t >> 6;
    const int l15 = lane & 15, kb = lane >> 4;
    const int swz = (l15 & 7) << 4;
    constexpr int BUFSZ = 8 * NFRAG * 1024;

    int baseA[MFRAG];
    #pragma unroll
    for (int m = 0; m < MFRAG; m++)
        baseA[m] = (((m * 16 + l15) * 1024) + kb * 16) ^ swz;

    char* chunk = ldsB + wid * (NFRAG * 1024);
    const f16* gw = Wp + (size_t)wid * NFRAG * KT * 512 + lane * 8;

    auto stage = [&](int s) {
        #pragma unroll
        for (int n = 0; n < NFRAG; n++)
            gload16(gw + ((size_t)n * KT + s) * 512,
                    chunk + (s & 1) * BUFSZ + n * 1024);
    };
    auto readB = [&](int s, half8 (&br)[NFRAG]) {
        #pragma unroll
        for (int n = 0; n < NFRAG; n++)
            br[n] = *(const half8*)(chunk + (s & 1) * BUFSZ + n * 1024 + lane * 16);
    };

    half8 a[2][MFRAG], br[2][NFRAG];
    floatx4 acc[MFRAG][NFRAG] = {};

    stage(0); stage(1);
    if constexpr (NFRAG == 4) VMCNT4; else VMCNT1;
    readB(0, br[0]);
    #pragma unroll
    for (int m = 0; m < MFRAG; m++) a[0][m] = *(const half8*)(lds + baseA[m]);

    #pragma unroll
    for (int kt = 0; kt < KT; kt++) {
        const int cur = kt & 1, nxt = cur ^ 1;
        __builtin_amdgcn_s_setprio(1);
        #pragma unroll
        for (int m = 0; m < MFRAG; m++)
            #pragma unroll
            for (int n = 0; n < NFRAG; n++)
                acc[m][n] = __builtin_amdgcn_mfma_f32_16x16x32_f16(
                    a[cur][m], br[cur][n], acc[m][n], 0, 0, 0);
        __builtin_amdgcn_s_setprio(0);
        if (kt + 2 < KT) {
            LGKM0;
            stage(kt + 2);
        }
        if (kt + 1 < KT) {
            if (kt + 2 < KT) { if constexpr (NFRAG == 4) VMCNT4; else VMCNT1; }
            else             { VMCNT0; }
            readB(kt + 1, br[nxt]);
            #pragma unroll
            for (int m = 0; m < MFRAG; m++)
                a[nxt][m] = *(const half8*)(lds + (baseA[m] ^ ((kt + 1) << 6)));
        }
    }

    __syncthreads();

    #pragma unroll
    for (int n = 0; n < NFRAG; n++) {
        const int col = wid * (NFRAG * 16) + n * 16 + l15;
        const float bb = bias[col];
        #pragma unroll
        for (int m = 0; m < MFRAG; m++) {
            #pragma unroll
            for (int e = 0; e < 4; e++) {
                const int row = m * 16 + kb * 4 + e;
                float v = acc[m][n][e] + bb;
                if constexpr (RELU) v = fmaxf(v, 0.0f);
                if constexpr (TOPANEL) {
                    *(f16*)(lds + pswz_b(row, col * 2)) = (f16)v;
                } else {
                    if (row < vend)
                        __builtin_nontemporal_store(v, &outf[(size_t)rmt[row] * SDIM_ + col]);
                }
            }
        }
    }
    if constexpr (TOPANEL) __syncthreads();
}

__global__ __launch_bounds__(512, 1) void branch_k(
    const f16* __restrict__ hT,
    const f16* __restrict__ U1p, const float* __restrict__ c1,
    const f16* __restrict__ U2p, const float* __restrict__ c2,
    const f16* __restrict__ U3p, const float* __restrict__ c3,
    const f16* __restrict__ Uop, const float* __restrict__ co,
    const int* __restrict__ cnt, const int* __restrict__ rowmap,
    float* __restrict__ out)
{
    extern __shared__ char lds[];
    char* ldsB = lds + 80 * 1024;
    const int d = blockIdx.x & 7, i = blockIdx.x >> 3;
    const int c = cnt[d];
    if (i * 80 >= c) return;
    const int vend = c - i * 80;
    const int* rmt = rowmap + d * CAP_ + i * 80;
    const int t = threadIdx.x;

    #pragma unroll
    for (int p = 0; p < 10; p++) {
        const int r   = p * 8 + (t >> 6);
        const int rr  = (r < vend) ? r : (vend - 1);
        const int c16 = t & 63;
        const int src = rmt[rr];
        half8 h = __builtin_nontemporal_load((const half8*)(hT + (size_t)src * H_ + c16 * 8));
        *(half8*)(lds + pswz_b(r, c16 * 16)) = h;
    }
    __syncthreads();

    const f16* u1 = U1p + (size_t)d * H_ * H_;
    const f16* u2 = U2p + (size_t)d * H_ * H_;
    const f16* u3 = U3p + (size_t)d * H_ * H_;
    const f16* uo = Uop + (size_t)d * H_ * SDIM_;

    layer_c<5, 4, 16, true,  true >(lds, ldsB, u1, c1 + d * H_,    nullptr, nullptr, 0);
    layer_c<5, 4, 16, true,  true >(lds, ldsB, u2, c2 + d * H_,    nullptr, nullptr, 0);
    layer_c<5, 4, 16, true,  true >(lds, ldsB, u3, c3 + d * H_,    nullptr, nullptr, 0);
    layer_c<5, 1, 16, false, false>(lds, ldsB, uo, co + d * SDIM_, out, rmt, vend);
}

// ---------------- host ----------------
extern "C" void kernel_launch(void* const* d_in, const int* in_sizes, int n_in,
                              void* d_out, int out_size, void* d_ws, size_t ws_size,
                              hipStream_t stream)
{
    const float* z  = (const float*)d_in[0];
    const int*   y  = (const int*)d_in[1];
    const float* W0 = (const float*)d_in[2];
    const float* b0 = (const float*)d_in[3];
    const float* W1 = (const float*)d_in[4];
    const float* b1 = (const float*)d_in[5];
    const float* W2 = (const float*)d_in[6];
    const float* b2 = (const float*)d_in[7];
    const float* W3 = (const float*)d_in[8];
    const float* b3 = (const float*)d_in[9];
    const float* U1 = (const float*)d_in[10];
    const float* c1 = (const float*)d_in[11];
    const float* U2 = (const float*)d_in[12];
    const float* c2 = (const float*)d_in[13];
    const float* U3 = (const float*)d_in[14];
    const float* c3 = (const float*)d_in[15];
    const float* Uo = (const float*)d_in[16];
    const float* co = (const float*)d_in[17];
    float* out = (float*)d_out;

    char* p = (char*)d_ws;
    auto take = [&](size_t nbytes) { char* r = p; p += (nbytes + 255) & ~(size_t)255; return r; };
    int* cnt    = (int*)take(ND_ * 4);
    int* rowmap = (int*)take((size_t)ND_ * CAP_ * 4);
    f16* W0t = (f16*)take((size_t)H_ * NZ_ * 2);
    f16* W1t = (f16*)take((size_t)H_ * H_ * 2);
    f16* W2t = (f16*)take((size_t)H_ * H_ * 2);
    f16* W3t = (f16*)take((size_t)H_ * H_ * 2);
    f16* U1t = (f16*)take((size_t)ND_ * H_ * H_ * 2);
    f16* U2t = (f16*)take((size_t)ND_ * H_ * H_ * 2);
    f16* U3t = (f16*)take((size_t)ND_ * H_ * H_ * 2);
    f16* Uot = (f16*)take((size_t)ND_ * SDIM_ * H_ * 2);
    f16* hT  = (f16*)take((size_t)B_ * H_ * 2);

    hipFuncSetAttribute((const void*)mega_k,   hipFuncAttributeMaxDynamicSharedMemorySize, 64 * 1024);
    hipFuncSetAttribute((const void*)branch_k, hipFuncAttributeMaxDynamicSharedMemorySize, 144 * 1024);

    tr_w_k<<<dim3(800), dim3(256), 0, stream>>>(W0, W1, W2, W3, W0t, W1t, W2t, W3t, cnt);

    mega_k<<<dim3(256), dim3(512), 64 * 1024, stream>>>(
        z, W0t, b0, W1t, b1, W2t, b2, W3t, b3, hT,
        U1, U2, U3, Uo, U1t, U2t, U3t, Uot,
        y, cnt, rowmap);

    branch_k<<<dim3(8 * NTB_), dim3(512), 144 * 1024, stream>>>(
        hT, U1t, c1, U2t, c2, U3t, c3, Uot, co, cnt, rowmap, out);
}